// Round 3
// baseline (79.313 us; speedup 1.0000x reference)
//
#include <hip/hip_runtime.h>

// ReduceBoundingBoxes NMS over (5,80,80) fp32, 2-kernel version.
//   flat[i,c] = X[c*n+i], n = 6400
//   valid = f0 > 0.9 ; b5 = (f0, f1, f0+f2, f1+f3, f4)
//   stable sort valid desc by score; greedy NMS on b5[:,1:5]; out row k =
//   kept ? b5_sorted[k] : 0.
//
// Exact identities used:
//  1) R(i) = #{j: sj>si || (sj==si && j<i)} is a bijection [0,n)->[0,n)
//     (strict total order). For valid i it equals the NMS rank (any j with
//     sj>si is itself valid); for invalid i, R(i) >= V. So thread i writes
//     row R(i) = (valid ? b5 : zeros) -> every row covered once, NO memset.
//  2) clamped-area==0 boxes have IoU exactly 0 with everything (monotone fp
//     rounding), so greedy NMS == greedy NMS over positive-area subset (~1).
//
// K_A: partial rank counts into distinct slots part[c*n+i] (no init, no
//      atomics); one extra block zeroes the ws counters.
// K_B: sum partials -> R(i), write row, collect positive-area boxes; the
//      LAST block (device-scope done counter) runs the tiny greedy NMS and
//      zeroes suppressed rows.

#define MAXM  256   // positive-area list capacity (M ~ 1 expected)
#define CHUNK 200   // score elements per rank chunk (800 B -> 16B aligned)

// ---- K_A: partial rank counts + counter zeroing ----
__global__ __launch_bounds__(256) void k_rankpart(
    const float* __restrict__ X, int* __restrict__ part,
    int* __restrict__ counters, int n, int groups, int chunks) {
  int b = blockIdx.x;
  if (b >= groups * chunks) {          // tail block: zero ws counters
    if (threadIdx.x < 8) counters[threadIdx.x] = 0;
    return;
  }
  int g = b / chunks, c = b - g * chunks;
  int i = g * 256 + threadIdx.x;
  int c0 = c * CHUNK, cend = min(c0 + CHUNK, n);
  float si = (i < n) ? X[i] : -1.f;
  int gt = 0, eq = 0;
  const float4* X4 = (const float4*)(X + c0);
  int nq = (cend - c0) >> 2;
  for (int q = 0; q < nq; ++q) {
    float4 v = X4[q];
    gt += (v.x > si) + (v.y > si) + (v.z > si) + (v.w > si);
    eq += (v.x == si) + (v.y == si) + (v.z == si) + (v.w == si);
  }
  for (int j = c0 + (nq << 2); j < cend; ++j) {
    float sj = X[j];
    gt += (sj > si); eq += (sj == si);
  }
  if (i >= c0 && i < cend) eq -= 1;    // self-equality; exclude
  int partial = gt;
  if (__any(eq > 0)) {                 // true fp tie in this chunk: rare
    int eqlt = 0;
    for (int j = c0; j < cend; ++j)
      eqlt += (X[j] == si) && (j < i);
    partial = gt + eqlt;               // exact for every lane (0 if no tie)
  }
  if (i < n) part[c * n + i] = partial;
}

// ---- K_B: rank-sum, row write, pos-area collect, last-block NMS ----
__global__ __launch_bounds__(256) void k_finish(
    const float* __restrict__ X, const int* __restrict__ part,
    float* __restrict__ out, float* __restrict__ list,
    int* __restrict__ counters, int n, int chunks, int nblocks) {
  __shared__ int sfix;
  const int t = threadIdx.x;
  int i = blockIdx.x * 256 + t;
  if (i < n) {
    float s = X[i];
    int r = 0;
    for (int c = 0; c < chunks; ++c) r += part[c * n + i];   // coalesced
    float* row = out + (size_t)r * 5;
    if (s > 0.9f) {
      float f1 = X[n + i], f2 = X[2 * n + i], f3 = X[3 * n + i], f4 = X[4 * n + i];
      float c2 = s + f2, c3 = f1 + f3;
      row[0] = s; row[1] = f1; row[2] = c2; row[3] = c3; row[4] = f4;
      // box = (f1, c2, c3, f4); reference-exact area arithmetic:
      float w = fmaxf(c3 - f1, 0.f);
      float h = fmaxf(f4 - c2, 0.f);
      float area = w * h;
      if (area > 0.f) {
        int p = atomicAdd(&counters[0], 1);
        if (p < MAXM) {
          float* e = list + (size_t)p * 6;
          e[0] = __int_as_float(r);
          e[1] = f1; e[2] = c2; e[3] = c3; e[4] = f4; e[5] = area;
        }
      }
    } else {
      row[0] = 0.f; row[1] = 0.f; row[2] = 0.f; row[3] = 0.f; row[4] = 0.f;
    }
  }
  // ---- last-block election ----
  __threadfence();                     // publish this thread's writes
  __syncthreads();                     // all threads of block fenced
  if (t == 0) {
    int old = atomicAdd(&counters[1], 1);   // device-scope by default
    sfix = (old == nblocks - 1);
  }
  __syncthreads();
  if (!sfix) return;
  __threadfence();                     // acquire side

  // ---- greedy NMS over positive-area boxes (M ~ 1) ----
  __shared__ int   srank[MAXM];
  __shared__ float sbox[MAXM][4];
  __shared__ float sarea[MAXM];
  __shared__ int   skeep[MAXM];
  __shared__ int   sflag;
  int M = __hip_atomic_load(&counters[0], __ATOMIC_ACQUIRE, __HIP_MEMORY_SCOPE_AGENT);
  if (M > MAXM) M = MAXM;
  for (int e = t; e < M; e += 256) {   // rank-sort (ranks distinct)
    float v0 = __hip_atomic_load(&list[e * 6 + 0], __ATOMIC_RELAXED, __HIP_MEMORY_SCOPE_AGENT);
    int r = __float_as_int(v0);
    int pos = 0;
    for (int m = 0; m < M; ++m) {
      float vm = __hip_atomic_load(&list[m * 6 + 0], __ATOMIC_RELAXED, __HIP_MEMORY_SCOPE_AGENT);
      pos += (__float_as_int(vm) < r);
    }
    srank[pos] = r;
    sbox[pos][0] = __hip_atomic_load(&list[e * 6 + 1], __ATOMIC_RELAXED, __HIP_MEMORY_SCOPE_AGENT);
    sbox[pos][1] = __hip_atomic_load(&list[e * 6 + 2], __ATOMIC_RELAXED, __HIP_MEMORY_SCOPE_AGENT);
    sbox[pos][2] = __hip_atomic_load(&list[e * 6 + 3], __ATOMIC_RELAXED, __HIP_MEMORY_SCOPE_AGENT);
    sbox[pos][3] = __hip_atomic_load(&list[e * 6 + 4], __ATOMIC_RELAXED, __HIP_MEMORY_SCOPE_AGENT);
    sarea[pos]   = __hip_atomic_load(&list[e * 6 + 5], __ATOMIC_RELAXED, __HIP_MEMORY_SCOPE_AGENT);
    skeep[pos] = 1;
  }
  __syncthreads();
  for (int s = 1; s < M; ++s) {
    if (t == 0) sflag = 0;
    __syncthreads();
    if (t < s && skeep[t]) {
      float ltx = fmaxf(sbox[t][0], sbox[s][0]);
      float lty = fmaxf(sbox[t][1], sbox[s][1]);
      float rbx = fminf(sbox[t][2], sbox[s][2]);
      float rby = fminf(sbox[t][3], sbox[s][3]);
      float w = fmaxf(rbx - ltx, 0.f);
      float h = fmaxf(rby - lty, 0.f);
      float inter = w * h;
      float uni = sarea[t] + sarea[s] - inter;
      if (inter / fmaxf(uni, 1e-9f) > 0.5f) sflag = 1;
    }
    __syncthreads();
    if (t == 0 && sflag) skeep[s] = 0;
    __syncthreads();
  }
  for (int e = t; e < M; e += 256) {
    if (!skeep[e]) {
      float* row = out + (size_t)srank[e] * 5;
      row[0] = 0.f; row[1] = 0.f; row[2] = 0.f; row[3] = 0.f; row[4] = 0.f;
    }
  }
}

// ---- Fallback: single-block kernel (used only if ws too small) ----
#define FB_NTH  1024
#define FB_MAXV 2048
__global__ __launch_bounds__(FB_NTH, 1) void nms_fallback(
    const float* __restrict__ X, float* __restrict__ out, int n, int out_n) {
  __shared__ float cscore[FB_MAXV];
  __shared__ unsigned int cidx[FB_MAXV];
  __shared__ int s_vcount, s_mcount, sflag;
  __shared__ int srank[MAXM];
  __shared__ float sbox[MAXM][4];
  __shared__ float sarea[MAXM];
  __shared__ int skeep[MAXM];
  __shared__ int prank[MAXM];
  __shared__ float pbox[MAXM][4];
  __shared__ float parea[MAXM];
  const int t = threadIdx.x;
  if (t == 0) { s_vcount = 0; s_mcount = 0; }
  float4* out4 = (float4*)out;
  int n4 = out_n >> 2;
  for (int i = t; i < n4; i += FB_NTH) out4[i] = make_float4(0.f, 0.f, 0.f, 0.f);
  for (int i = (n4 << 2) + t; i < out_n; i += FB_NTH) out[i] = 0.f;
  __syncthreads();
  for (int i = t; i < n; i += FB_NTH) {
    float s = X[i];
    if (s > 0.9f) {
      int p = atomicAdd(&s_vcount, 1);
      if (p < FB_MAXV) { cscore[p] = s; cidx[p] = (unsigned int)i; }
    }
  }
  __syncthreads();
  const int V = min(s_vcount, FB_MAXV);
  for (int e = t; e < V; e += FB_NTH) {
    float s = cscore[e];
    unsigned int idx = cidx[e];
    int rank = 0;
    for (int m = 0; m < V; ++m) {
      float sm = cscore[m];
      rank += (sm > s) || (sm == s && cidx[m] < idx);
    }
    float f1 = X[n + idx], f2 = X[2 * n + idx], f3 = X[3 * n + idx], f4 = X[4 * n + idx];
    float c2 = s + f2, c3 = f1 + f3;
    float* row = out + (size_t)rank * 5;
    row[0] = s; row[1] = f1; row[2] = c2; row[3] = c3; row[4] = f4;
    float w = fmaxf(c3 - f1, 0.f), h = fmaxf(f4 - c2, 0.f);
    float area = w * h;
    if (area > 0.f) {
      int p = atomicAdd(&s_mcount, 1);
      if (p < MAXM) {
        prank[p] = rank;
        pbox[p][0] = f1; pbox[p][1] = c2; pbox[p][2] = c3; pbox[p][3] = f4;
        parea[p] = area;
      }
    }
  }
  __syncthreads();
  const int M = min(s_mcount, MAXM);
  for (int e = t; e < M; e += FB_NTH) {
    int r = prank[e];
    int pos = 0;
    for (int m = 0; m < M; ++m) pos += (prank[m] < r);
    srank[pos] = r;
    sbox[pos][0] = pbox[e][0]; sbox[pos][1] = pbox[e][1];
    sbox[pos][2] = pbox[e][2]; sbox[pos][3] = pbox[e][3];
    sarea[pos] = parea[e];
    skeep[pos] = 1;
  }
  __syncthreads();
  for (int s = 1; s < M; ++s) {
    if (t == 0) sflag = 0;
    __syncthreads();
    if (t < s && skeep[t]) {
      float ltx = fmaxf(sbox[t][0], sbox[s][0]);
      float lty = fmaxf(sbox[t][1], sbox[s][1]);
      float rbx = fminf(sbox[t][2], sbox[s][2]);
      float rby = fminf(sbox[t][3], sbox[s][3]);
      float w = fmaxf(rbx - ltx, 0.f), h = fmaxf(rby - lty, 0.f);
      float inter = w * h;
      float uni = sarea[t] + sarea[s] - inter;
      if (inter / fmaxf(uni, 1e-9f) > 0.5f) sflag = 1;
    }
    __syncthreads();
    if (t == 0 && sflag) skeep[s] = 0;
    __syncthreads();
  }
  for (int e = t; e < M; e += FB_NTH) {
    if (!skeep[e]) {
      float* row = out + (size_t)srank[e] * 5;
      row[0] = 0.f; row[1] = 0.f; row[2] = 0.f; row[3] = 0.f; row[4] = 0.f;
    }
  }
}

extern "C" void kernel_launch(void* const* d_in, const int* in_sizes, int n_in,
                              void* d_out, int out_size, void* d_ws, size_t ws_size,
                              hipStream_t stream) {
  const float* X = (const float*)d_in[0];
  float* out = (float*)d_out;
  int n = in_sizes[0] / 5;   // 6400
  int groups = (n + 255) / 256;              // 25
  int chunks = (n + CHUNK - 1) / CHUNK;      // 32
  size_t part_bytes = (size_t)chunks * n * sizeof(int);
  size_t need = 256 + part_bytes + (size_t)MAXM * 6 * sizeof(float);
  if (ws_size >= need) {
    int* counters = (int*)d_ws;                                  // [0]=cnt [1]=done
    int* part = (int*)((char*)d_ws + 256);
    float* list = (float*)((char*)d_ws + 256 + part_bytes);
    hipLaunchKernelGGL(k_rankpart, dim3(groups * chunks + 1), dim3(256), 0, stream,
                       X, part, counters, n, groups, chunks);
    hipLaunchKernelGGL(k_finish, dim3(groups), dim3(256), 0, stream,
                       X, part, out, list, counters, n, chunks, groups);
  } else {
    hipLaunchKernelGGL(nms_fallback, dim3(1), dim3(FB_NTH), 0, stream, X, out, n, out_size);
  }
}

// Round 4
// 73.767 us; speedup vs baseline: 1.0752x; 1.0752x over previous
//
#include <hip/hip_runtime.h>

// ReduceBoundingBoxes NMS over (5,80,80) fp32. 2 kernels, no fences, no
// global atomics; all cross-kernel ordering via stream order.
//   flat[i,c] = X[c*n+i], n = 6400
//   valid = f0 > 0.9 ; b5 = (f0, f1, f0+f2, f1+f3, f4)
//   stable sort valid desc by score; greedy NMS on b5[:,1:5]; row k =
//   kept ? b5_sorted[k] : 0.
//
// Exact identities:
//  1) For valid i, rank depends only on the VALID subset (any outranking j
//     has sj >= si > 0.9). Key K = (bits(s)<<32) | ~idx gives a strict total
//     order matching (desc score, asc idx); rank = #{Km > Ke} -- order-free,
//     self-excluded. Ranks of valid entries are a bijection onto [0,V), so
//     rows [V,n) are exactly the all-zero rows.
//  2) Clamped-area==0 boxes have IoU exactly 0 with everything (monotone fp
//     rounding) -> greedy NMS == greedy NMS over positive-area subset (~1
//     box here). Those rows are deferred to k_fix via flags/list (slot =
//     rank -> no counters, no ws init needed).

#define MAXM   1024   // positive-area capacity for the fixup block
#define MAXW   512    // per-block candidate worklist capacity (~26 expected)
#define MAXKEY 6400   // LDS key capacity == n

__global__ __launch_bounds__(256) void k_main(
    const float* __restrict__ X, float* __restrict__ out,
    int* __restrict__ vout, int* __restrict__ flags, float* __restrict__ list,
    int n, int out_n) {
  __shared__ unsigned long long skey[MAXKEY];
  __shared__ int swork[MAXW];
  __shared__ int lcnt, wcnt;
  const int t = threadIdx.x, b = blockIdx.x, nb = gridDim.x;
  if (t == 0) { lcnt = 0; wcnt = 0; }
  __syncthreads();

  // ---- stage all valid keys into LDS (order irrelevant); build this
  //      block's deterministic worklist (i % nb == b) ----
  const float4* X4 = (const float4*)X;
  int nq = n >> 2;
  for (int q = t; q < nq; q += 256) {
    float4 v = X4[q];
    int i0 = q << 2;
    float vs[4] = {v.x, v.y, v.z, v.w};
#pragma unroll
    for (int c = 0; c < 4; ++c) {
      if (vs[c] > 0.9f) {
        int i = i0 + c;
        int p = atomicAdd(&lcnt, 1);
        if (p < MAXKEY)
          skey[p] = ((unsigned long long)__float_as_uint(vs[c]) << 32) |
                    (unsigned int)(~i);
        if ((i % nb) == b) {
          int w = atomicAdd(&wcnt, 1);
          if (w < MAXW) swork[w] = i;
        }
      }
    }
  }
  for (int i = (nq << 2) + t; i < n; i += 256) {   // tail (n%4 != 0)
    float s = X[i];
    if (s > 0.9f) {
      int p = atomicAdd(&lcnt, 1);
      if (p < MAXKEY)
        skey[p] = ((unsigned long long)__float_as_uint(s) << 32) |
                  (unsigned int)(~i);
      if ((i % nb) == b) {
        int w = atomicAdd(&wcnt, 1);
        if (w < MAXW) swork[w] = i;
      }
    }
  }
  __syncthreads();
  const int V = min(lcnt, MAXKEY);
  if (b == 0 && t == 0) *vout = V;

  // ---- rank + emit this block's candidates ----
  const int W = min(wcnt, MAXW);
  for (int e = t; e < W; e += 256) {
    int i = swork[e];
    float s  = X[i];
    float f1 = X[n + i], f2 = X[2 * n + i], f3 = X[3 * n + i], f4 = X[4 * n + i];
    unsigned long long Ke =
        ((unsigned long long)__float_as_uint(s) << 32) | (unsigned int)(~i);
    int rank = 0;
    for (int m = 0; m < V; ++m)        // broadcast ds_read_b64, no conflicts
      rank += (skey[m] > Ke);
    float c2 = s + f2, c3 = f1 + f3;
    // box = (f1, c2, c3, f4); reference-exact area arithmetic:
    float w = fmaxf(c3 - f1, 0.f);
    float h = fmaxf(f4 - c2, 0.f);
    float area = w * h;
    if (area > 0.f) {                  // defer to k_fix (slot = rank)
      float* L = list + (size_t)rank * 8;
      L[0] = s; L[1] = f1; L[2] = c2; L[3] = c3; L[4] = f4; L[5] = area;
      flags[rank] = 1;
    } else {                           // zero-area: always kept, write now
      float* row = out + (size_t)rank * 5;
      row[0] = s; row[1] = f1; row[2] = c2; row[3] = c3; row[4] = f4;
      flags[rank] = 0;
    }
  }

  // ---- rows [V, n) are exactly the zero rows: coalesced fill ----
  for (int f = 5 * V + b * 256 + t; f < out_n; f += nb * 256)
    out[f] = 0.f;
}

__global__ __launch_bounds__(256) void k_fix(
    const float* __restrict__ list, const int* __restrict__ flags,
    const int* __restrict__ vptr, float* __restrict__ out) {
  __shared__ int   sm, sflag;
  __shared__ int   sr[MAXM];
  __shared__ int   sord[MAXM];
  __shared__ float sb[MAXM][5];
  __shared__ float sa[MAXM];
  __shared__ int   skeep[MAXM];
  const int t = threadIdx.x;
  if (t == 0) sm = 0;
  __syncthreads();
  const int V = *vptr;
  for (int r = t; r < V; r += 256)
    if (flags[r]) { int p = atomicAdd(&sm, 1); if (p < MAXM) sr[p] = r; }
  __syncthreads();
  const int M = min(sm, MAXM);
  for (int e = t; e < M; e += 256) {   // sort by rank (ranks distinct)
    int r = sr[e];
    int pos = 0;
    for (int m = 0; m < M; ++m) pos += (sr[m] < r);
    const float* L = list + (size_t)r * 8;
    sord[pos] = r;
    sb[pos][0] = L[0]; sb[pos][1] = L[1]; sb[pos][2] = L[2];
    sb[pos][3] = L[3]; sb[pos][4] = L[4];
    sa[pos] = L[5];
    skeep[pos] = 1;
  }
  __syncthreads();
  // greedy NMS, reference-exact fp; box = sb[][1..4]
  for (int i = 1; i < M; ++i) {
    if (t == 0) sflag = 0;
    __syncthreads();
    if (t < i && skeep[t]) {
      float ltx = fmaxf(sb[t][1], sb[i][1]);
      float lty = fmaxf(sb[t][2], sb[i][2]);
      float rbx = fminf(sb[t][3], sb[i][3]);
      float rby = fminf(sb[t][4], sb[i][4]);
      float w = fmaxf(rbx - ltx, 0.f);
      float h = fmaxf(rby - lty, 0.f);
      float inter = w * h;
      float uni = sa[t] + sa[i] - inter;
      if (inter / fmaxf(uni, 1e-9f) > 0.5f) sflag = 1;
    }
    __syncthreads();
    if (t == 0 && sflag) skeep[i] = 0;
    __syncthreads();
  }
  for (int e = t; e < M; e += 256) {
    float* row = out + (size_t)sord[e] * 5;
    if (skeep[e]) {
      row[0] = sb[e][0]; row[1] = sb[e][1]; row[2] = sb[e][2];
      row[3] = sb[e][3]; row[4] = sb[e][4];
    } else {
      row[0] = 0.f; row[1] = 0.f; row[2] = 0.f; row[3] = 0.f; row[4] = 0.f;
    }
  }
}

// ---- Fallback: single-block kernel (only if ws too small; never here) ----
#define FB_NTH  1024
#define FB_MAXV 2048
#define FB_MAXM 256
__global__ __launch_bounds__(FB_NTH, 1) void nms_fallback(
    const float* __restrict__ X, float* __restrict__ out, int n, int out_n) {
  __shared__ float cscore[FB_MAXV];
  __shared__ unsigned int cidx[FB_MAXV];
  __shared__ int s_vcount, s_mcount, sflag;
  __shared__ int srank[FB_MAXM];
  __shared__ float sbox[FB_MAXM][4];
  __shared__ float sarea[FB_MAXM];
  __shared__ int skeep[FB_MAXM];
  __shared__ int prank[FB_MAXM];
  __shared__ float pbox[FB_MAXM][4];
  __shared__ float parea[FB_MAXM];
  const int t = threadIdx.x;
  if (t == 0) { s_vcount = 0; s_mcount = 0; }
  float4* out4 = (float4*)out;
  int n4 = out_n >> 2;
  for (int i = t; i < n4; i += FB_NTH) out4[i] = make_float4(0.f, 0.f, 0.f, 0.f);
  for (int i = (n4 << 2) + t; i < out_n; i += FB_NTH) out[i] = 0.f;
  __syncthreads();
  for (int i = t; i < n; i += FB_NTH) {
    float s = X[i];
    if (s > 0.9f) {
      int p = atomicAdd(&s_vcount, 1);
      if (p < FB_MAXV) { cscore[p] = s; cidx[p] = (unsigned int)i; }
    }
  }
  __syncthreads();
  const int V = min(s_vcount, FB_MAXV);
  for (int e = t; e < V; e += FB_NTH) {
    float s = cscore[e];
    unsigned int idx = cidx[e];
    int rank = 0;
    for (int m = 0; m < V; ++m) {
      float sm = cscore[m];
      rank += (sm > s) || (sm == s && cidx[m] < idx);
    }
    float f1 = X[n + idx], f2 = X[2 * n + idx], f3 = X[3 * n + idx], f4 = X[4 * n + idx];
    float c2 = s + f2, c3 = f1 + f3;
    float* row = out + (size_t)rank * 5;
    row[0] = s; row[1] = f1; row[2] = c2; row[3] = c3; row[4] = f4;
    float w = fmaxf(c3 - f1, 0.f), h = fmaxf(f4 - c2, 0.f);
    float area = w * h;
    if (area > 0.f) {
      int p = atomicAdd(&s_mcount, 1);
      if (p < FB_MAXM) {
        prank[p] = rank;
        pbox[p][0] = f1; pbox[p][1] = c2; pbox[p][2] = c3; pbox[p][3] = f4;
        parea[p] = area;
      }
    }
  }
  __syncthreads();
  const int M = min(s_mcount, FB_MAXM);
  for (int e = t; e < M; e += FB_NTH) {
    int r = prank[e];
    int pos = 0;
    for (int m = 0; m < M; ++m) pos += (prank[m] < r);
    srank[pos] = r;
    sbox[pos][0] = pbox[e][0]; sbox[pos][1] = pbox[e][1];
    sbox[pos][2] = pbox[e][2]; sbox[pos][3] = pbox[e][3];
    sarea[pos] = parea[e];
    skeep[pos] = 1;
  }
  __syncthreads();
  for (int s = 1; s < M; ++s) {
    if (t == 0) sflag = 0;
    __syncthreads();
    if (t < s && skeep[t]) {
      float ltx = fmaxf(sbox[t][0], sbox[s][0]);
      float lty = fmaxf(sbox[t][1], sbox[s][1]);
      float rbx = fminf(sbox[t][2], sbox[s][2]);
      float rby = fminf(sbox[t][3], sbox[s][3]);
      float w = fmaxf(rbx - ltx, 0.f), h = fmaxf(rby - lty, 0.f);
      float inter = w * h;
      float uni = sarea[t] + sarea[s] - inter;
      if (inter / fmaxf(uni, 1e-9f) > 0.5f) sflag = 1;
    }
    __syncthreads();
    if (t == 0 && sflag) skeep[s] = 0;
    __syncthreads();
  }
  for (int e = t; e < M; e += FB_NTH) {
    if (!skeep[e]) {
      float* row = out + (size_t)srank[e] * 5;
      row[0] = 0.f; row[1] = 0.f; row[2] = 0.f; row[3] = 0.f; row[4] = 0.f;
    }
  }
}

extern "C" void kernel_launch(void* const* d_in, const int* in_sizes, int n_in,
                              void* d_out, int out_size, void* d_ws, size_t ws_size,
                              hipStream_t stream) {
  const float* X = (const float*)d_in[0];
  float* out = (float*)d_out;
  int n = in_sizes[0] / 5;   // 6400
  int nb = (n + 255) / 256;  // 25
  // ws layout: [0..63] vout | [256, 256+4n) flags | [align16) list n*8 floats
  size_t flags_off = 256;
  size_t list_off = (flags_off + (size_t)n * sizeof(int) + 15) & ~(size_t)15;
  size_t need = list_off + (size_t)n * 8 * sizeof(float);
  if (ws_size >= need && n <= MAXKEY) {
    int* vout = (int*)d_ws;
    int* flags = (int*)((char*)d_ws + flags_off);
    float* list = (float*)((char*)d_ws + list_off);
    hipLaunchKernelGGL(k_main, dim3(nb), dim3(256), 0, stream,
                       X, out, vout, flags, list, n, out_size);
    hipLaunchKernelGGL(k_fix, dim3(1), dim3(256), 0, stream,
                       list, flags, vout, out);
  } else {
    hipLaunchKernelGGL(nms_fallback, dim3(1), dim3(FB_NTH), 0, stream, X, out, n, out_size);
  }
}